// Round 6
// baseline (90.313 us; speedup 1.0000x reference)
//
#include <hip/hip_runtime.h>
#include <hip/hip_fp16.h>
#include <math.h>

// Problem constants (from reference):
//   B=4, N=1024 -> 4096 atoms; IN_CH=OUT_CH=16; N_BASIS=16; N_FEAT=19
//   centers = linspace(0,3.5,16) -> c_f = f*(3.5/15); GAMMA = 3.5/16
//   out /= sqrt(24)
#define IN_CH 16
#define OUT_CH 16
#define N_BASIS 16
#define N_FEAT 19                    // 16 basis + 3 rhat
#define Y_STRIDE (N_FEAT * OUT_CH)   // 304 halfs per atom, layout y[a][f][o]
#define GAMMA_INV (16.0f / 3.5f)
#define CENTER_STEP (3.5f / 15.0f)
#define INV_SQRT_NNORM 0.20412414523193154f  // 1/sqrt(24), folded into y
#define APB 16                       // atoms per block in kernel A
#define EPB 32                       // edges per block in kernel B (2 windows)

// ---------------------------------------------------------------------------
// Kernel A: y[a, f, o] = (1/sqrt(24)) * sum_i W[f,o,i] * x[a,i], fp16.
// 16 atoms per block: W row W[f,o,:] loaded ONCE into registers (4 float4),
// reused across 16 atoms -> W L2 traffic 78 MB -> 4.9 MB vs 1-atom blocks.
// t -> (f = t>>4, o = t&15) matches y's [f][o] layout; stores coalesced
// (608 B contiguous per atom). Also zeroes out (harness poisons d_out).
// ---------------------------------------------------------------------------
__global__ __launch_bounds__(320) void precompute_y(
    const float* __restrict__ x, const float* __restrict__ W,
    __half* __restrict__ y, float* __restrict__ out, int n_atoms) {
  __shared__ float xs[APB][IN_CH];
  const int t = threadIdx.x;
  const int a0 = blockIdx.x * APB;

  if (t < APB * IN_CH) {
    const int idx = a0 * IN_CH + t;
    const bool ok = idx < n_atoms * IN_CH;
    xs[t >> 4][t & 15] = ok ? x[idx] : 0.0f;
    if (ok) out[idx] = 0.0f;  // zero output (poisoned before every launch)
  }

  float4 w0, w1, w2, w3;
  if (t < Y_STRIDE) {
    const float4* w4 = (const float4*)(W + t * IN_CH);  // t = f*16+o
    w0 = w4[0]; w1 = w4[1]; w2 = w4[2]; w3 = w4[3];
  }
  __syncthreads();

  if (t < Y_STRIDE) {
#pragma unroll
    for (int al = 0; al < APB; ++al) {
      if (a0 + al >= n_atoms) break;
      const float* xv = xs[al];
      float acc = w0.x * xv[0] + w0.y * xv[1] + w0.z * xv[2] + w0.w * xv[3] +
                  w1.x * xv[4] + w1.y * xv[5] + w1.z * xv[6] + w1.w * xv[7] +
                  w2.x * xv[8] + w2.y * xv[9] + w2.z * xv[10] + w2.w * xv[11] +
                  w3.x * xv[12] + w3.y * xv[13] + w3.z * xv[14] + w3.w * xv[15];
      // fold 1/sqrt(24) before fp16 rounding (~5x smaller abs error)
      y[(size_t)(a0 + al) * Y_STRIDE + t] = __float2half(acc * INV_SQRT_NNORM);
    }
  }
}

// ---------------------------------------------------------------------------
// Kernel B: msg[e,o] = sum_f feat[e,f] * y[src_e, f, o] -> atomicAdd out[dst].
// 8 lanes per edge, 2 channels per lane (half2): halves VMEM/LDS instruction
// count vs 16-lane R5 while keeping the same coalesced 32 B/feature pattern.
// 32 edges per 256-thread block as two independent 16-edge dedup windows
// (fully unrolled scan — no serial walks). One fp32 atomic per unique
// (dst, channel) pair per window.
// ---------------------------------------------------------------------------
__global__ __launch_bounds__(256) void edge_scatter(
    const __half* __restrict__ y, const float* __restrict__ edge_vec,
    const int* __restrict__ edge_src, const int* __restrict__ edge_dst,
    float* __restrict__ out, int E) {
  __shared__ float feat[EPB][20];   // stride 20: s,s+8 alias -> 2-way (free)
  __shared__ float msg[EPB][OUT_CH];
  __shared__ int dsts[EPB];

  const int t = threadIdx.x;
  const int w = t >> 7;            // window 0/1
  const int rem = t & 127;
  const int el = rem & 15;         // edge within window
  const int h = rem >> 4;          // 0..7 -> channels {2h, 2h+1}
  const int s = w * 16 + el;       // slot 0..31
  const int e = blockIdx.x * EPB + s;
  const bool valid = (e < E);

  float vx = 0.f, vy = 0.f, vz = 0.f;
  int src = 0;
  if (valid) {
    vx = edge_vec[3 * e + 0];
    vy = edge_vec[3 * e + 1];
    vz = edge_vec[3 * e + 2];
    src = edge_src[e];
    if (h == 0) dsts[s] = edge_dst[e];
  } else if (h == 0) {
    dsts[s] = -1 - s;  // unique sentinel: never merged, never emitted
  }
  const float r = sqrtf(vx * vx + vy * vy + vz * vz);

  // basis features 2h, 2h+1: exp(-((r - c)/gamma)^2)
  const float t0 = (r - CENTER_STEP * (float)(2 * h)) * GAMMA_INV;
  const float t1 = (r - CENTER_STEP * (float)(2 * h + 1)) * GAMMA_INV;
  feat[s][2 * h] = __expf(-t0 * t0);
  feat[s][2 * h + 1] = __expf(-t1 * t1);
  if (h < 3) {
    // reference: rhat = where(r > 1e-10, vec / max(r,1e-10), 0)
    const float inv = (r > 1e-10f) ? (1.0f / r) : 0.0f;
    const float comp = (h == 0) ? vx : ((h == 1) ? vy : vz);
    feat[s][N_BASIS + h] = comp * inv;
  }
  __syncthreads();

  float a0 = 0.f, a1 = 0.f;
  if (valid) {
    // y[src][f][2h..2h+1] as one half2 per feature (4 B aligned: 304,2h even)
    const __half2* __restrict__ yrow =
        (const __half2*)(y + (size_t)src * Y_STRIDE + 2 * h);
#pragma unroll
    for (int f = 0; f < N_FEAT; ++f) {
      const float2 yv = __half22float2(yrow[f * (OUT_CH / 2)]);
      const float ff = feat[s][f];
      a0 += ff * yv.x;
      a1 += ff * yv.y;
    }
  }
  msg[s][2 * h] = a0;
  msg[s][2 * h + 1] = a1;
  __syncthreads();

  // Fixed-window dedup: first slot in window with a given dst emits the sum.
  const int wb = w * 16;
  const int mydst = dsts[s];
  int leader = el;
#pragma unroll
  for (int k = 0; k < 16; ++k) {
    if (dsts[wb + k] == mydst) { leader = k; break; }
  }
  if (leader == el && mydst >= 0) {
    float s0 = 0.f, s1 = 0.f;
#pragma unroll
    for (int k = 0; k < 16; ++k) {
      if (k >= el && dsts[wb + k] == mydst) {
        s0 += msg[wb + k][2 * h];
        s1 += msg[wb + k][2 * h + 1];
      }
    }
    atomicAdd(&out[mydst * OUT_CH + 2 * h], s0);      // 1/sqrt(24) in y
    atomicAdd(&out[mydst * OUT_CH + 2 * h + 1], s1);
  }
}

// ---------------------------------------------------------------------------
// Fallback (only if ws too small for y): direct per-edge evaluation.
// ---------------------------------------------------------------------------
__global__ __launch_bounds__(256) void edge_direct(
    const float* __restrict__ x, const float* __restrict__ W,
    const float* __restrict__ edge_vec, const int* __restrict__ edge_src,
    const int* __restrict__ edge_dst, float* __restrict__ out, int E) {
  __shared__ float Ws[N_FEAT * OUT_CH * IN_CH];
  __shared__ float feat[16][N_FEAT];
  __shared__ float xs[16][IN_CH];

  const int t = threadIdx.x;
  for (int i = t; i < N_FEAT * OUT_CH * IN_CH; i += 256) Ws[i] = W[i];

  const int eg = t >> 4;
  const int o = t & 15;
  const int e = blockIdx.x * 16 + eg;
  const bool valid = (e < E);

  float vx = 0.f, vy = 0.f, vz = 0.f;
  int src = 0, dst = 0;
  if (valid) {
    vx = edge_vec[3 * e + 0];
    vy = edge_vec[3 * e + 1];
    vz = edge_vec[3 * e + 2];
    src = edge_src[e];
    dst = edge_dst[e];
    xs[eg][o] = x[src * IN_CH + o];
  }
  const float r = sqrtf(vx * vx + vy * vy + vz * vz);
  const float tt = (r - CENTER_STEP * (float)o) * GAMMA_INV;
  feat[eg][o] = __expf(-tt * tt);
  if (o < 3) {
    const float inv = (r > 1e-10f) ? (1.0f / r) : 0.0f;
    const float comp = (o == 0) ? vx : ((o == 1) ? vy : vz);
    feat[eg][N_BASIS + o] = comp * inv;
  }
  __syncthreads();

  if (valid) {
    float acc = 0.f;
#pragma unroll
    for (int f = 0; f < N_FEAT; ++f) {
      const float* wrow = &Ws[(f * OUT_CH + o) * IN_CH];
      float dot = 0.f;
#pragma unroll
      for (int i = 0; i < IN_CH; ++i) dot += wrow[i] * xs[eg][i];
      acc += feat[eg][f] * dot;
    }
    atomicAdd(&out[dst * OUT_CH + o], acc * INV_SQRT_NNORM);
  }
}

extern "C" void kernel_launch(void* const* d_in, const int* in_sizes, int n_in,
                              void* d_out, int out_size, void* d_ws,
                              size_t ws_size, hipStream_t stream) {
  const float* x = (const float*)d_in[0];        // [n_atoms, 16]
  const float* W = (const float*)d_in[1];        // [19, 16, 16]
  const float* edge_vec = (const float*)d_in[2]; // [E, 3]
  const int* edge_src = (const int*)d_in[3];     // [E]
  const int* edge_dst = (const int*)d_in[4];     // [E]
  float* out = (float*)d_out;

  const int E = in_sizes[3];
  const int n_atoms = in_sizes[0] / IN_CH;

  const size_t y_bytes = (size_t)n_atoms * Y_STRIDE * sizeof(__half);
  if (ws_size >= y_bytes) {
    __half* y = (__half*)d_ws;
    precompute_y<<<(n_atoms + APB - 1) / APB, 320, 0, stream>>>(x, W, y, out,
                                                               n_atoms);
    edge_scatter<<<(E + EPB - 1) / EPB, 256, 0, stream>>>(y, edge_vec, edge_src,
                                                          edge_dst, out, E);
  } else {
    hipMemsetAsync(out, 0, (size_t)out_size * sizeof(float), stream);
    edge_direct<<<(E + 15) / 16, 256, 0, stream>>>(x, W, edge_vec, edge_src,
                                                   edge_dst, out, E);
  }
}

// Round 7
// 78.615 us; speedup vs baseline: 1.1488x; 1.1488x over previous
//
#include <hip/hip_runtime.h>
#include <hip/hip_fp16.h>
#include <math.h>

// Problem constants (from reference):
//   B=4, N=1024 -> 4096 atoms; IN_CH=OUT_CH=16; N_BASIS=16; N_FEAT=19
//   centers = linspace(0,3.5,16) -> c_f = f*(3.5/15); GAMMA = 3.5/16
//   out /= sqrt(24)
#define IN_CH 16
#define OUT_CH 16
#define N_BASIS 16
#define N_FEAT 19                    // 16 basis + 3 rhat
#define Y_STRIDE (N_FEAT * OUT_CH)   // 304 halfs per atom, layout y[a][f][o]
#define GAMMA_INV (16.0f / 3.5f)
#define CENTER_STEP (3.5f / 15.0f)
#define INV_SQRT_NNORM 0.20412414523193154f  // 1/sqrt(24), folded into y
#define EPB 32                       // edges per block (two 16-edge windows)

// ---------------------------------------------------------------------------
// Kernel A (R5 exact, known-good): y[a,f,o] = (1/sqrt24)*sum_i W[f,o,i]*x[a,i]
// fp16, layout [a][f][o]. One block/atom; t -> (f=t/16, o=t%16). Also zeroes
// this atom's out slice (harness poisons d_out before every timed launch).
// ---------------------------------------------------------------------------
__global__ __launch_bounds__(320) void precompute_y(
    const float* __restrict__ x, const float* __restrict__ W,
    __half* __restrict__ y, float* __restrict__ out) {
  __shared__ float xs[IN_CH];
  const int a = blockIdx.x;
  const int t = threadIdx.x;
  if (t < IN_CH) {
    xs[t] = x[a * IN_CH + t];
    out[a * OUT_CH + t] = 0.0f;
  }
  __syncthreads();
  if (t < Y_STRIDE) {
    const float4* w4 = (const float4*)(W + t * IN_CH);
    float acc = 0.f;
#pragma unroll
    for (int q = 0; q < 4; ++q) {
      float4 w = w4[q];
      acc += w.x * xs[4 * q + 0] + w.y * xs[4 * q + 1] +
             w.z * xs[4 * q + 2] + w.w * xs[4 * q + 3];
    }
    // fold 1/sqrt(24) before fp16 rounding (~5x smaller abs error)
    y[(size_t)a * Y_STRIDE + t] = __float2half(acc * INV_SQRT_NNORM);
  }
}

// ---------------------------------------------------------------------------
// Kernel B: msg[e,o] = sum_f feat[e,f] * y[src_e,f,o] -> atomicAdd out[dst].
// 8 lanes/edge, 2 channels/lane via half2, with the CHANNEL index FAST:
//   h = t & 7 (channels 2h,2h+1), el = (t>>3) & 15, w = t>>7.
// Lanes 0-7 read edge el=0's 16 channels = 32 B contiguous (coalesced, same
// footprint as R5) while halving VMEM/LDS instruction count and thread count
// vs R5. Two independent fully-unrolled 16-slot dedup windows per block
// (edge list is dst-sorted within each periodic-shift chunk); one fp32
// atomic per unique (dst, channel) per window.
// ---------------------------------------------------------------------------
__global__ __launch_bounds__(256) void edge_scatter(
    const __half* __restrict__ y, const float* __restrict__ edge_vec,
    const int* __restrict__ edge_src, const int* __restrict__ edge_dst,
    float* __restrict__ out, int E) {
  __shared__ float feat[EPB][20];     // stride 20 floats: conflict-benign
  __shared__ float2 msg2[EPB][8];     // msg2[s][h] = channels {2h, 2h+1}
  __shared__ int dsts[EPB];

  const int t = threadIdx.x;
  const int h = t & 7;                // FAST: channel pair {2h, 2h+1}
  const int el = (t >> 3) & 15;       // edge within window
  const int w = t >> 7;               // window 0/1
  const int s = w * 16 + el;          // slot 0..31
  const int e = blockIdx.x * EPB + s;
  const bool valid = (e < E);

  float vx = 0.f, vy = 0.f, vz = 0.f;
  int src = 0;
  if (valid) {
    vx = edge_vec[3 * e + 0];
    vy = edge_vec[3 * e + 1];
    vz = edge_vec[3 * e + 2];
    src = edge_src[e];
    if (h == 0) dsts[s] = edge_dst[e];
  } else if (h == 0) {
    dsts[s] = -1 - s;  // unique sentinel: never merged, never emitted
  }
  const float r = sqrtf(vx * vx + vy * vy + vz * vz);

  // basis features 2h, 2h+1: exp(-((r - c)/gamma)^2)
  const float t0 = (r - CENTER_STEP * (float)(2 * h)) * GAMMA_INV;
  const float t1 = (r - CENTER_STEP * (float)(2 * h + 1)) * GAMMA_INV;
  feat[s][2 * h] = __expf(-t0 * t0);
  feat[s][2 * h + 1] = __expf(-t1 * t1);
  if (h < 3) {
    // reference: rhat = where(r > 1e-10, vec / max(r,1e-10), 0)
    const float inv = (r > 1e-10f) ? (1.0f / r) : 0.0f;
    const float comp = (h == 0) ? vx : ((h == 1) ? vy : vz);
    feat[s][N_BASIS + h] = comp * inv;
  }
  __syncthreads();

  float a0 = 0.f, a1 = 0.f;
  if (valid) {
    // y[src][f][2h..2h+1]: one half2 per feature; lanes h=0..7 of one edge
    // cover 32 B contiguous -> coalesced quarter-wave segments.
    const __half2* __restrict__ yrow =
        (const __half2*)(y + (size_t)src * Y_STRIDE + 2 * h);
#pragma unroll
    for (int f = 0; f < N_FEAT; ++f) {
      const float2 yv = __half22float2(yrow[f * (OUT_CH / 2)]);
      const float ff = feat[s][f];
      a0 += ff * yv.x;
      a1 += ff * yv.y;
    }
  }
  msg2[s][h] = make_float2(a0, a1);
  __syncthreads();

  // Fixed-window dedup (fully unrolled, no serial walks) + atomic emit.
  const int wb = w * 16;
  const int mydst = dsts[s];
  int leader = el;
#pragma unroll
  for (int k = 0; k < 16; ++k) {
    if (dsts[wb + k] == mydst) { leader = k; break; }
  }
  if (leader == el && mydst >= 0) {
    float s0 = 0.f, s1 = 0.f;
#pragma unroll
    for (int k = 0; k < 16; ++k) {
      if (k >= el && dsts[wb + k] == mydst) {
        const float2 m = msg2[wb + k][h];
        s0 += m.x;
        s1 += m.y;
      }
    }
    atomicAdd(&out[mydst * OUT_CH + 2 * h], s0);      // 1/sqrt(24) in y
    atomicAdd(&out[mydst * OUT_CH + 2 * h + 1], s1);
  }
}

// ---------------------------------------------------------------------------
// Fallback (only if ws too small for y): direct per-edge evaluation.
// ---------------------------------------------------------------------------
__global__ __launch_bounds__(256) void edge_direct(
    const float* __restrict__ x, const float* __restrict__ W,
    const float* __restrict__ edge_vec, const int* __restrict__ edge_src,
    const int* __restrict__ edge_dst, float* __restrict__ out, int E) {
  __shared__ float Ws[N_FEAT * OUT_CH * IN_CH];
  __shared__ float feat[16][N_FEAT];
  __shared__ float xs[16][IN_CH];

  const int t = threadIdx.x;
  for (int i = t; i < N_FEAT * OUT_CH * IN_CH; i += 256) Ws[i] = W[i];

  const int eg = t >> 4;
  const int o = t & 15;
  const int e = blockIdx.x * 16 + eg;
  const bool valid = (e < E);

  float vx = 0.f, vy = 0.f, vz = 0.f;
  int src = 0, dst = 0;
  if (valid) {
    vx = edge_vec[3 * e + 0];
    vy = edge_vec[3 * e + 1];
    vz = edge_vec[3 * e + 2];
    src = edge_src[e];
    dst = edge_dst[e];
    xs[eg][o] = x[src * IN_CH + o];
  }
  const float r = sqrtf(vx * vx + vy * vy + vz * vz);
  const float tt = (r - CENTER_STEP * (float)o) * GAMMA_INV;
  feat[eg][o] = __expf(-tt * tt);
  if (o < 3) {
    const float inv = (r > 1e-10f) ? (1.0f / r) : 0.0f;
    const float comp = (o == 0) ? vx : ((o == 1) ? vy : vz);
    feat[eg][N_BASIS + o] = comp * inv;
  }
  __syncthreads();

  if (valid) {
    float acc = 0.f;
#pragma unroll
    for (int f = 0; f < N_FEAT; ++f) {
      const float* wrow = &Ws[(f * OUT_CH + o) * IN_CH];
      float dot = 0.f;
#pragma unroll
      for (int i = 0; i < IN_CH; ++i) dot += wrow[i] * xs[eg][i];
      acc += feat[eg][f] * dot;
    }
    atomicAdd(&out[dst * OUT_CH + o], acc * INV_SQRT_NNORM);
  }
}

extern "C" void kernel_launch(void* const* d_in, const int* in_sizes, int n_in,
                              void* d_out, int out_size, void* d_ws,
                              size_t ws_size, hipStream_t stream) {
  const float* x = (const float*)d_in[0];        // [n_atoms, 16]
  const float* W = (const float*)d_in[1];        // [19, 16, 16]
  const float* edge_vec = (const float*)d_in[2]; // [E, 3]
  const int* edge_src = (const int*)d_in[3];     // [E]
  const int* edge_dst = (const int*)d_in[4];     // [E]
  float* out = (float*)d_out;

  const int E = in_sizes[3];
  const int n_atoms = in_sizes[0] / IN_CH;

  const size_t y_bytes = (size_t)n_atoms * Y_STRIDE * sizeof(__half);
  if (ws_size >= y_bytes) {
    __half* y = (__half*)d_ws;
    precompute_y<<<n_atoms, 320, 0, stream>>>(x, W, y, out);
    edge_scatter<<<(E + EPB - 1) / EPB, 256, 0, stream>>>(y, edge_vec, edge_src,
                                                          edge_dst, out, E);
  } else {
    hipMemsetAsync(out, 0, (size_t)out_size * sizeof(float), stream);
    edge_direct<<<(E + 15) / 16, 256, 0, stream>>>(x, W, edge_vec, edge_src,
                                                   edge_dst, out, E);
  }
}

// Round 8
// 76.768 us; speedup vs baseline: 1.1764x; 1.0241x over previous
//
#include <hip/hip_runtime.h>
#include <hip/hip_fp16.h>
#include <math.h>

// Problem constants (from reference):
//   B=4, N=1024 -> 4096 atoms; IN_CH=OUT_CH=16; N_BASIS=16; N_FEAT=19
//   centers = linspace(0,3.5,16) -> c_f = f*(3.5/15); GAMMA = 3.5/16
//   out /= sqrt(24)
#define IN_CH 16
#define OUT_CH 16
#define N_BASIS 16
#define N_FEAT 19                    // 16 basis + 3 rhat
#define Y_STRIDE (N_FEAT * OUT_CH)   // 304 halfs per atom, layout y[a][f][o]
#define GAMMA_INV (16.0f / 3.5f)
#define CENTER_STEP (3.5f / 15.0f)
#define INV_SQRT_NNORM 0.20412414523193154f  // 1/sqrt(24), folded into y
#define APB 16                       // atoms per block in kernel A
#define EPB 64                       // edges per block in kernel B (4 windows)

// ---------------------------------------------------------------------------
// Kernel A: y[a,f,o] = (1/sqrt24)*sum_i W[f,o,i]*x[a,i], fp16, layout [a][f][o]
// (known-good from R5/R7). 16 atoms per block: thread t's W row W[f,o,:]
// (t = f*16+o) is loaded ONCE into registers and reused across 16 atoms ->
// W L2 traffic 78 MB -> 4.9 MB; blocks 4096 -> 256. Stores remain coalesced
// (608 B contiguous per atom). Also zeroes out (harness poisons d_out).
// ---------------------------------------------------------------------------
__global__ __launch_bounds__(320) void precompute_y(
    const float* __restrict__ x, const float* __restrict__ W,
    __half* __restrict__ y, float* __restrict__ out, int n_atoms) {
  __shared__ float xs[APB][IN_CH];
  const int t = threadIdx.x;
  const int a0 = blockIdx.x * APB;

  if (t < APB * IN_CH) {
    const int idx = a0 * IN_CH + t;
    const bool ok = idx < n_atoms * IN_CH;
    xs[t >> 4][t & 15] = ok ? x[idx] : 0.0f;
    if (ok) out[idx] = 0.0f;  // zero output (poisoned before every launch)
  }

  float4 w0, w1, w2, w3;
  if (t < Y_STRIDE) {
    const float4* w4 = (const float4*)(W + t * IN_CH);  // t = f*16 + o
    w0 = w4[0]; w1 = w4[1]; w2 = w4[2]; w3 = w4[3];
  }
  __syncthreads();

  if (t < Y_STRIDE) {
#pragma unroll
    for (int al = 0; al < APB; ++al) {
      if (a0 + al >= n_atoms) break;
      const float* xv = xs[al];
      float acc = w0.x * xv[0] + w0.y * xv[1] + w0.z * xv[2] + w0.w * xv[3] +
                  w1.x * xv[4] + w1.y * xv[5] + w1.z * xv[6] + w1.w * xv[7] +
                  w2.x * xv[8] + w2.y * xv[9] + w2.z * xv[10] + w2.w * xv[11] +
                  w3.x * xv[12] + w3.y * xv[13] + w3.z * xv[14] + w3.w * xv[15];
      // fold 1/sqrt(24) before fp16 rounding (~5x smaller abs error)
      y[(size_t)(a0 + al) * Y_STRIDE + t] = __float2half(acc * INV_SQRT_NNORM);
    }
  }
}

// ---------------------------------------------------------------------------
// Kernel B: msg[e,o] = sum_f feat[e,f] * y[src_e,f,o] -> atomicAdd out[dst].
// 4 lanes/edge, 4 channels/lane, CHANNEL index FAST (proven R7 axis):
//   h = t & 3 (channels 4h..4h+3), el = (t>>2) & 15, w = t>>6 (4 windows).
// Lanes 0-3 of an edge read 32 B contiguous per feature as ONE dwordx2 each
// -> same coalesced footprint as R5/R7, half the VMEM/LDS instructions of R7.
// Dedup: fully-unrolled 16-slot window scan (edge list is dst-sorted within
// each periodic-shift chunk); unique (dst,channel) pairs emit fp32 atomics.
// ---------------------------------------------------------------------------
__global__ __launch_bounds__(256) void edge_scatter(
    const __half* __restrict__ y, const float* __restrict__ edge_vec,
    const int* __restrict__ edge_src, const int* __restrict__ edge_dst,
    float* __restrict__ out, int E) {
  __shared__ float feat[EPB][20];     // stride 20 floats: conflict-benign
  __shared__ float4 msg4[EPB][4];     // msg4[s][h] = channels {4h..4h+3}
  __shared__ int dsts[EPB];

  const int t = threadIdx.x;
  const int h = t & 3;                // FAST: channel quad {4h..4h+3}
  const int el = (t >> 2) & 15;       // edge within window
  const int w = t >> 6;               // window 0..3
  const int s = w * 16 + el;          // slot 0..63
  const int e = blockIdx.x * EPB + s;
  const bool valid = (e < E);

  float vx = 0.f, vy = 0.f, vz = 0.f;
  int src = 0;
  if (valid) {
    vx = edge_vec[3 * e + 0];
    vy = edge_vec[3 * e + 1];
    vz = edge_vec[3 * e + 2];
    src = edge_src[e];
    if (h == 0) dsts[s] = edge_dst[e];
  } else if (h == 0) {
    dsts[s] = -1 - s;  // unique sentinel: never merged, never emitted
  }
  const float r = sqrtf(vx * vx + vy * vy + vz * vz);

  // basis features 4h..4h+3: exp(-((r - c)/gamma)^2)
#pragma unroll
  for (int j = 0; j < 4; ++j) {
    const float tb = (r - CENTER_STEP * (float)(4 * h + j)) * GAMMA_INV;
    feat[s][4 * h + j] = __expf(-tb * tb);
  }
  if (h < 3) {
    // reference: rhat = where(r > 1e-10, vec / max(r,1e-10), 0)
    const float inv = (r > 1e-10f) ? (1.0f / r) : 0.0f;
    const float comp = (h == 0) ? vx : ((h == 1) ? vy : vz);
    feat[s][N_BASIS + h] = comp * inv;
  }
  __syncthreads();

  float a0 = 0.f, a1 = 0.f, a2 = 0.f, a3 = 0.f;
  if (valid) {
    // y[src][f][4h..4h+3]: one 8-B load per feature (addr 8-B aligned:
    // src*608 + 8h bytes). Lanes h=0..3 cover 32 B contiguous -> coalesced.
    const float2* __restrict__ yrow =
        (const float2*)(y + (size_t)src * Y_STRIDE + 4 * h);
#pragma unroll
    for (int f = 0; f < N_FEAT; ++f) {
      const float2 raw = yrow[f * (OUT_CH / 4)];
      const __half2 p0 = *(const __half2*)&raw.x;
      const __half2 p1 = *(const __half2*)&raw.y;
      const float2 v0 = __half22float2(p0);
      const float2 v1 = __half22float2(p1);
      const float ff = feat[s][f];
      a0 += ff * v0.x;
      a1 += ff * v0.y;
      a2 += ff * v1.x;
      a3 += ff * v1.y;
    }
  }
  msg4[s][h] = make_float4(a0, a1, a2, a3);
  __syncthreads();

  // Fixed-window dedup (fully unrolled, no serial walks) + atomic emit.
  const int wb = w * 16;
  const int mydst = dsts[s];
  int leader = el;
#pragma unroll
  for (int k = 0; k < 16; ++k) {
    if (dsts[wb + k] == mydst) { leader = k; break; }
  }
  if (leader == el && mydst >= 0) {
    float s0 = 0.f, s1 = 0.f, s2 = 0.f, s3 = 0.f;
#pragma unroll
    for (int k = 0; k < 16; ++k) {
      if (k >= el && dsts[wb + k] == mydst) {
        const float4 m = msg4[wb + k][h];
        s0 += m.x; s1 += m.y; s2 += m.z; s3 += m.w;
      }
    }
    float* base = &out[mydst * OUT_CH + 4 * h];
    atomicAdd(base + 0, s0);   // 1/sqrt(24) already folded into y
    atomicAdd(base + 1, s1);
    atomicAdd(base + 2, s2);
    atomicAdd(base + 3, s3);
  }
}

// ---------------------------------------------------------------------------
// Fallback (only if ws too small for y): direct per-edge evaluation.
// ---------------------------------------------------------------------------
__global__ __launch_bounds__(256) void edge_direct(
    const float* __restrict__ x, const float* __restrict__ W,
    const float* __restrict__ edge_vec, const int* __restrict__ edge_src,
    const int* __restrict__ edge_dst, float* __restrict__ out, int E) {
  __shared__ float Ws[N_FEAT * OUT_CH * IN_CH];
  __shared__ float feat[16][N_FEAT];
  __shared__ float xs[16][IN_CH];

  const int t = threadIdx.x;
  for (int i = t; i < N_FEAT * OUT_CH * IN_CH; i += 256) Ws[i] = W[i];

  const int eg = t >> 4;
  const int o = t & 15;
  const int e = blockIdx.x * 16 + eg;
  const bool valid = (e < E);

  float vx = 0.f, vy = 0.f, vz = 0.f;
  int src = 0, dst = 0;
  if (valid) {
    vx = edge_vec[3 * e + 0];
    vy = edge_vec[3 * e + 1];
    vz = edge_vec[3 * e + 2];
    src = edge_src[e];
    dst = edge_dst[e];
    xs[eg][o] = x[src * IN_CH + o];
  }
  const float r = sqrtf(vx * vx + vy * vy + vz * vz);
  const float tt = (r - CENTER_STEP * (float)o) * GAMMA_INV;
  feat[eg][o] = __expf(-tt * tt);
  if (o < 3) {
    const float inv = (r > 1e-10f) ? (1.0f / r) : 0.0f;
    const float comp = (o == 0) ? vx : ((o == 1) ? vy : vz);
    feat[eg][N_BASIS + o] = comp * inv;
  }
  __syncthreads();

  if (valid) {
    float acc = 0.f;
#pragma unroll
    for (int f = 0; f < N_FEAT; ++f) {
      const float* wrow = &Ws[(f * OUT_CH + o) * IN_CH];
      float dot = 0.f;
#pragma unroll
      for (int i = 0; i < IN_CH; ++i) dot += wrow[i] * xs[eg][i];
      acc += feat[eg][f] * dot;
    }
    atomicAdd(&out[dst * OUT_CH + o], acc * INV_SQRT_NNORM);
  }
}

extern "C" void kernel_launch(void* const* d_in, const int* in_sizes, int n_in,
                              void* d_out, int out_size, void* d_ws,
                              size_t ws_size, hipStream_t stream) {
  const float* x = (const float*)d_in[0];        // [n_atoms, 16]
  const float* W = (const float*)d_in[1];        // [19, 16, 16]
  const float* edge_vec = (const float*)d_in[2]; // [E, 3]
  const int* edge_src = (const int*)d_in[3];     // [E]
  const int* edge_dst = (const int*)d_in[4];     // [E]
  float* out = (float*)d_out;

  const int E = in_sizes[3];
  const int n_atoms = in_sizes[0] / IN_CH;

  const size_t y_bytes = (size_t)n_atoms * Y_STRIDE * sizeof(__half);
  if (ws_size >= y_bytes) {
    __half* y = (__half*)d_ws;
    precompute_y<<<(n_atoms + APB - 1) / APB, 320, 0, stream>>>(x, W, y, out,
                                                               n_atoms);
    edge_scatter<<<(E + EPB - 1) / EPB, 256, 0, stream>>>(y, edge_vec, edge_src,
                                                          edge_dst, out, E);
  } else {
    hipMemsetAsync(out, 0, (size_t)out_size * sizeof(float), stream);
    edge_direct<<<(E + 15) / 16, 256, 0, stream>>>(x, W, edge_vec, edge_src,
                                                   edge_dst, out, E);
  }
}